// Round 1
// baseline (665.908 us; speedup 1.0000x reference)
//
#include <hip/hip_runtime.h>

#define MAXDEG 64

// Build per-dst edge lists (bucketed CSR, cap MAXDEG slots/node).
__global__ __launch_bounds__(256) void k_fill_csr(const int* __restrict__ ei, int E,
                                                  int* __restrict__ cursor, int* __restrict__ csr) {
    int e = blockIdx.x * 256 + threadIdx.x;
    if (e >= E) return;
    int src = ei[e];
    int dst = ei[E + e];
    int slot = atomicAdd(&cursor[dst], 1);
    if (slot < MAXDEG) csr[(size_t)dst * MAXDEG + slot] = src;
}

// Y = X @ Wa ; Z = X @ Wb + bias.  X: n x 64, Wa/Wb: 64x64 row-major [j][k].
__global__ __launch_bounds__(256) void k_gemm(const float* __restrict__ X,
                                              const float* __restrict__ Wa,
                                              const float* __restrict__ Wb,
                                              const float* __restrict__ bias,
                                              float* __restrict__ Y, float* __restrict__ Z, int n) {
    __shared__ float XsT[64][68];   // transposed x tile: [col j][node r], pad->272B rows (16B aligned)
    __shared__ float Wc[64][128];   // [j][k]: k<64 -> Wa, k>=64 -> Wb
    int tid = threadIdx.x;
    int n0 = blockIdx.x * 64;

    for (int i = tid; i < 64 * 64; i += 256) {
        int j = i >> 6, k = i & 63;
        Wc[j][k]      = Wa[i];
        Wc[j][64 + k] = Wb[i];
    }
    for (int i = tid; i < 64 * 64; i += 256) {
        int r = i >> 6, c = i & 63;
        int nn = n0 + r;
        XsT[c][r] = (nn < n) ? X[(size_t)nn * 64 + c] : 0.f;
    }
    __syncthreads();

    int tx = tid & 15, ty = tid >> 4;   // tx: 8 cols (4 of Y, 4 of Z), ty: 4 nodes
    float acc[4][8];
#pragma unroll
    for (int u = 0; u < 4; ++u)
#pragma unroll
        for (int v = 0; v < 8; ++v) acc[u][v] = 0.f;

    for (int j = 0; j < 64; ++j) {
        float4 xv = *(const float4*)&XsT[j][ty * 4];
        float4 wa = *(const float4*)&Wc[j][tx * 4];
        float4 wb = *(const float4*)&Wc[j][64 + tx * 4];
        float xs[4] = {xv.x, xv.y, xv.z, xv.w};
        float ws[8] = {wa.x, wa.y, wa.z, wa.w, wb.x, wb.y, wb.z, wb.w};
#pragma unroll
        for (int u = 0; u < 4; ++u)
#pragma unroll
            for (int v = 0; v < 8; ++v) acc[u][v] += xs[u] * ws[v];
    }

    float4 bv = *(const float4*)&bias[tx * 4];
#pragma unroll
    for (int u = 0; u < 4; ++u) {
        int nn = n0 + ty * 4 + u;
        if (nn < n) {
            *(float4*)&Y[(size_t)nn * 64 + tx * 4] =
                make_float4(acc[u][0], acc[u][1], acc[u][2], acc[u][3]);
            *(float4*)&Z[(size_t)nn * 64 + tx * 4] =
                make_float4(acc[u][4] + bv.x, acc[u][5] + bv.y, acc[u][6] + bv.z, acc[u][7] + bv.w);
        }
    }
}

// h[node] = relu( sum_{src in csr[node]} Y[src] / max(deg,1) + Z[node] ).  One wave per node.
__global__ __launch_bounds__(256) void k_gather_l1(const float* __restrict__ Y,
                                                   const float* __restrict__ Z,
                                                   const int* __restrict__ deg,
                                                   const int* __restrict__ csr,
                                                   float* __restrict__ H, int n) {
    int wave = threadIdx.x >> 6;
    int lane = threadIdx.x & 63;
    int node = blockIdx.x * 4 + wave;
    if (node >= n) return;
    int d = deg[node];
    int dc = d > MAXDEG ? MAXDEG : d;
    const int* lst = &csr[(size_t)node * MAXDEG];
    float acc = 0.f;
    int e = 0;
    for (; e + 4 <= dc; e += 4) {
        int s0 = lst[e], s1 = lst[e + 1], s2 = lst[e + 2], s3 = lst[e + 3];
        float a0 = Y[(size_t)s0 * 64 + lane];
        float a1 = Y[(size_t)s1 * 64 + lane];
        float a2 = Y[(size_t)s2 * 64 + lane];
        float a3 = Y[(size_t)s3 * 64 + lane];
        acc += (a0 + a1) + (a2 + a3);
    }
    for (; e < dc; ++e) acc += Y[(size_t)lst[e] * 64 + lane];
    float v = acc / (float)(d > 1 ? d : 1) + Z[(size_t)node * 64 + lane];
    H[(size_t)node * 64 + lane] = v > 0.f ? v : 0.f;
}

// Layer-2 gather fused with readout: pool[batch[node]] += dot(relu(...), Wro).
__global__ __launch_bounds__(256) void k_gather_l2(const float* __restrict__ Y,
                                                   const float* __restrict__ Z,
                                                   const int* __restrict__ deg,
                                                   const int* __restrict__ csr,
                                                   const int* __restrict__ batch,
                                                   const float* __restrict__ Wro,
                                                   float* __restrict__ pool, int n) {
    int wave = threadIdx.x >> 6;
    int lane = threadIdx.x & 63;
    int node = blockIdx.x * 4 + wave;
    if (node >= n) return;
    int d = deg[node];
    int dc = d > MAXDEG ? MAXDEG : d;
    const int* lst = &csr[(size_t)node * MAXDEG];
    float acc = 0.f;
    int e = 0;
    for (; e + 4 <= dc; e += 4) {
        int s0 = lst[e], s1 = lst[e + 1], s2 = lst[e + 2], s3 = lst[e + 3];
        float a0 = Y[(size_t)s0 * 64 + lane];
        float a1 = Y[(size_t)s1 * 64 + lane];
        float a2 = Y[(size_t)s2 * 64 + lane];
        float a3 = Y[(size_t)s3 * 64 + lane];
        acc += (a0 + a1) + (a2 + a3);
    }
    for (; e < dc; ++e) acc += Y[(size_t)lst[e] * 64 + lane];
    float v = acc / (float)(d > 1 ? d : 1) + Z[(size_t)node * 64 + lane];
    v = v > 0.f ? v : 0.f;
    float s = v * Wro[lane];
#pragma unroll
    for (int off = 32; off; off >>= 1) s += __shfl_xor(s, off, 64);
    if (lane == 0) atomicAdd(&pool[batch[node]], s);
}

// out[g] = pool[g] / count(batch==g) + bro.  batch is sorted -> binary search.
__global__ void k_final(const float* __restrict__ pool, const int* __restrict__ batch,
                        const float* __restrict__ bro, float* __restrict__ out, int n, int G) {
    int g = blockIdx.x * blockDim.x + threadIdx.x;
    if (g >= G) return;
    int lo = 0, hi = n;
    while (lo < hi) { int mid = (lo + hi) >> 1; if (batch[mid] < g) lo = mid + 1; else hi = mid; }
    int lb0 = lo;
    lo = 0; hi = n;
    while (lo < hi) { int mid = (lo + hi) >> 1; if (batch[mid] < g + 1) lo = mid + 1; else hi = mid; }
    int c = lo - lb0;
    out[g] = pool[g] / (float)(c > 1 ? c : 1) + bro[0];
}

extern "C" void kernel_launch(void* const* d_in, const int* in_sizes, int n_in,
                              void* d_out, int out_size, void* d_ws, size_t ws_size,
                              hipStream_t stream) {
    const float* x   = (const float*)d_in[0];
    const float* Wl1 = (const float*)d_in[1];
    const float* bl1 = (const float*)d_in[2];
    const float* Wr1 = (const float*)d_in[3];
    const float* Wl2 = (const float*)d_in[4];
    const float* bl2 = (const float*)d_in[5];
    const float* Wr2 = (const float*)d_in[6];
    const float* Wro = (const float*)d_in[7];
    const float* bro = (const float*)d_in[8];
    const int* ei    = (const int*)d_in[9];
    const int* batch = (const int*)d_in[10];

    int N = in_sizes[0] / 64;
    int E = in_sizes[9] / 2;
    int G = out_size;

    char* ws = (char*)d_ws;
    size_t off = 0;
    auto carve = [&](size_t bytes) {
        void* p = ws + off;
        off += (bytes + 255) & ~(size_t)255;
        return p;
    };
    int*   cursor = (int*)carve((size_t)N * 4);
    int*   csr    = (int*)carve((size_t)N * MAXDEG * 4);
    float* y      = (float*)carve((size_t)N * 64 * 4);
    float* z      = (float*)carve((size_t)N * 64 * 4);
    float* h      = (float*)carve((size_t)N * 64 * 4);
    float* pool   = (float*)carve((size_t)G * 4);

    hipMemsetAsync(cursor, 0, (size_t)N * 4, stream);
    hipMemsetAsync(pool, 0, (size_t)G * 4, stream);

    k_fill_csr<<<(E + 255) / 256, 256, 0, stream>>>(ei, E, cursor, csr);
    k_gemm<<<(N + 63) / 64, 256, 0, stream>>>(x, Wl1, Wr1, bl1, y, z, N);
    k_gather_l1<<<(N + 3) / 4, 256, 0, stream>>>(y, z, cursor, csr, h, N);
    k_gemm<<<(N + 63) / 64, 256, 0, stream>>>(h, Wl2, Wr2, bl2, y, z, N);
    k_gather_l2<<<(N + 3) / 4, 256, 0, stream>>>(y, z, cursor, csr, batch, Wro, pool, N);
    k_final<<<(G + 255) / 256, 256, 0, stream>>>(pool, batch, bro, (float*)d_out, N, G);
}

// Round 2
// 650.795 us; speedup vs baseline: 1.0232x; 1.0232x over previous
//
#include <hip/hip_runtime.h>

#define MAXDEG 64

__device__ __forceinline__ float4 f4add(float4 a, float4 b) {
    return make_float4(a.x + b.x, a.y + b.y, a.z + b.z, a.w + b.w);
}

// Build per-dst edge lists (bucketed CSR, cap MAXDEG slots/node).
__global__ __launch_bounds__(256) void k_fill_csr(const int* __restrict__ ei, int E,
                                                  int* __restrict__ cursor, int* __restrict__ csr) {
    int e = blockIdx.x * 256 + threadIdx.x;
    if (e >= E) return;
    int src = ei[e];
    int dst = ei[E + e];
    int slot = atomicAdd(&cursor[dst], 1);
    if (slot < MAXDEG) csr[(size_t)dst * MAXDEG + slot] = src;
}

// Y = X @ Wa ; Z = X @ Wb + bias.  X: n x 64, Wa/Wb: 64x64 row-major [j][k].
__global__ __launch_bounds__(256) void k_gemm(const float* __restrict__ X,
                                              const float* __restrict__ Wa,
                                              const float* __restrict__ Wb,
                                              const float* __restrict__ bias,
                                              float* __restrict__ Y, float* __restrict__ Z, int n) {
    __shared__ float XsT[64][68];
    __shared__ float Wc[64][128];
    int tid = threadIdx.x;
    int n0 = blockIdx.x * 64;

    for (int i = tid; i < 64 * 64; i += 256) {
        int j = i >> 6, k = i & 63;
        Wc[j][k]      = Wa[i];
        Wc[j][64 + k] = Wb[i];
    }
    for (int i = tid; i < 64 * 64; i += 256) {
        int r = i >> 6, c = i & 63;
        int nn = n0 + r;
        XsT[c][r] = (nn < n) ? X[(size_t)nn * 64 + c] : 0.f;
    }
    __syncthreads();

    int tx = tid & 15, ty = tid >> 4;
    float acc[4][8];
#pragma unroll
    for (int u = 0; u < 4; ++u)
#pragma unroll
        for (int v = 0; v < 8; ++v) acc[u][v] = 0.f;

    for (int j = 0; j < 64; ++j) {
        float4 xv = *(const float4*)&XsT[j][ty * 4];
        float4 wa = *(const float4*)&Wc[j][tx * 4];
        float4 wb = *(const float4*)&Wc[j][64 + tx * 4];
        float xs[4] = {xv.x, xv.y, xv.z, xv.w};
        float ws[8] = {wa.x, wa.y, wa.z, wa.w, wb.x, wb.y, wb.z, wb.w};
#pragma unroll
        for (int u = 0; u < 4; ++u)
#pragma unroll
            for (int v = 0; v < 8; ++v) acc[u][v] += xs[u] * ws[v];
    }

    float4 bv = *(const float4*)&bias[tx * 4];
#pragma unroll
    for (int u = 0; u < 4; ++u) {
        int nn = n0 + ty * 4 + u;
        if (nn < n) {
            *(float4*)&Y[(size_t)nn * 64 + tx * 4] =
                make_float4(acc[u][0], acc[u][1], acc[u][2], acc[u][3]);
            *(float4*)&Z[(size_t)nn * 64 + tx * 4] =
                make_float4(acc[u][4] + bv.x, acc[u][5] + bv.y, acc[u][6] + bv.z, acc[u][7] + bv.w);
        }
    }
}

// Gather core: 4 nodes per wave, 16 lanes per node, float4 per lane.
// Each group runs an independent idx->rows chain; ~20 loads in flight per wave.
#define GATHER_CORE(ACC_DONE)                                                        \
    int t = threadIdx.x;                                                             \
    int lane = t & 63;                                                               \
    int g = lane >> 4, q = lane & 15;                                                \
    int node = blockIdx.x * 16 + (t >> 6) * 4 + g;                                   \
    if (node >= n) return;                                                           \
    int d = deg[node];                                                               \
    int dc = d > MAXDEG ? MAXDEG : d;                                                \
    const int* lst = &csr[(size_t)node * MAXDEG];                                    \
    float4 acc = make_float4(0.f, 0.f, 0.f, 0.f);                                    \
    int e = 0;                                                                       \
    for (; e + 8 <= dc; e += 8) {                                                    \
        int4 ia = *(const int4*)&lst[e];                                             \
        int4 ib = *(const int4*)&lst[e + 4];                                         \
        float4 a0 = *(const float4*)&Y[(size_t)ia.x * 64 + q * 4];                   \
        float4 a1 = *(const float4*)&Y[(size_t)ia.y * 64 + q * 4];                   \
        float4 a2 = *(const float4*)&Y[(size_t)ia.z * 64 + q * 4];                   \
        float4 a3 = *(const float4*)&Y[(size_t)ia.w * 64 + q * 4];                   \
        float4 b0 = *(const float4*)&Y[(size_t)ib.x * 64 + q * 4];                   \
        float4 b1 = *(const float4*)&Y[(size_t)ib.y * 64 + q * 4];                   \
        float4 b2 = *(const float4*)&Y[(size_t)ib.z * 64 + q * 4];                   \
        float4 b3 = *(const float4*)&Y[(size_t)ib.w * 64 + q * 4];                   \
        acc = f4add(acc, f4add(f4add(a0, a1), f4add(a2, a3)));                       \
        acc = f4add(acc, f4add(f4add(b0, b1), f4add(b2, b3)));                       \
    }                                                                                \
    if (e + 4 <= dc) {                                                               \
        int4 ia = *(const int4*)&lst[e];                                             \
        float4 a0 = *(const float4*)&Y[(size_t)ia.x * 64 + q * 4];                   \
        float4 a1 = *(const float4*)&Y[(size_t)ia.y * 64 + q * 4];                   \
        float4 a2 = *(const float4*)&Y[(size_t)ia.z * 64 + q * 4];                   \
        float4 a3 = *(const float4*)&Y[(size_t)ia.w * 64 + q * 4];                   \
        acc = f4add(acc, f4add(f4add(a0, a1), f4add(a2, a3)));                       \
        e += 4;                                                                      \
    }                                                                                \
    for (; e < dc; ++e) {                                                            \
        float4 a = *(const float4*)&Y[(size_t)lst[e] * 64 + q * 4];                  \
        acc = f4add(acc, a);                                                         \
    }                                                                                \
    float dd = (float)(d > 1 ? d : 1);                                               \
    float4 z = *(const float4*)&Z[(size_t)node * 64 + q * 4];                        \
    float4 v;                                                                        \
    v.x = acc.x / dd + z.x;                                                          \
    v.y = acc.y / dd + z.y;                                                          \
    v.z = acc.z / dd + z.z;                                                          \
    v.w = acc.w / dd + z.w;                                                          \
    v.x = v.x > 0.f ? v.x : 0.f;                                                     \
    v.y = v.y > 0.f ? v.y : 0.f;                                                     \
    v.z = v.z > 0.f ? v.z : 0.f;                                                     \
    v.w = v.w > 0.f ? v.w : 0.f;                                                     \
    ACC_DONE

__global__ __launch_bounds__(256) void k_gather_l1(const float* __restrict__ Y,
                                                   const float* __restrict__ Z,
                                                   const int* __restrict__ deg,
                                                   const int* __restrict__ csr,
                                                   float* __restrict__ H, int n) {
    GATHER_CORE({ *(float4*)&H[(size_t)node * 64 + q * 4] = v; })
}

__global__ __launch_bounds__(256) void k_gather_l2(const float* __restrict__ Y,
                                                   const float* __restrict__ Z,
                                                   const int* __restrict__ deg,
                                                   const int* __restrict__ csr,
                                                   const int* __restrict__ batch,
                                                   const float* __restrict__ Wro,
                                                   float* __restrict__ pool, int n) {
    GATHER_CORE({
        float4 w = *(const float4*)&Wro[q * 4];
        float s = v.x * w.x + v.y * w.y + v.z * w.z + v.w * w.w;
        s += __shfl_xor(s, 1, 16);
        s += __shfl_xor(s, 2, 16);
        s += __shfl_xor(s, 4, 16);
        s += __shfl_xor(s, 8, 16);
        if (q == 0) atomicAdd(&pool[batch[node]], s);
    })
}

// out[g] = pool[g] / count(batch==g) + bro.  batch is sorted -> binary search.
__global__ void k_final(const float* __restrict__ pool, const int* __restrict__ batch,
                        const float* __restrict__ bro, float* __restrict__ out, int n, int G) {
    int g = blockIdx.x * blockDim.x + threadIdx.x;
    if (g >= G) return;
    int lo = 0, hi = n;
    while (lo < hi) { int mid = (lo + hi) >> 1; if (batch[mid] < g) lo = mid + 1; else hi = mid; }
    int lb0 = lo;
    lo = 0; hi = n;
    while (lo < hi) { int mid = (lo + hi) >> 1; if (batch[mid] < g + 1) lo = mid + 1; else hi = mid; }
    int c = lo - lb0;
    out[g] = pool[g] / (float)(c > 1 ? c : 1) + bro[0];
}

extern "C" void kernel_launch(void* const* d_in, const int* in_sizes, int n_in,
                              void* d_out, int out_size, void* d_ws, size_t ws_size,
                              hipStream_t stream) {
    const float* x   = (const float*)d_in[0];
    const float* Wl1 = (const float*)d_in[1];
    const float* bl1 = (const float*)d_in[2];
    const float* Wr1 = (const float*)d_in[3];
    const float* Wl2 = (const float*)d_in[4];
    const float* bl2 = (const float*)d_in[5];
    const float* Wr2 = (const float*)d_in[6];
    const float* Wro = (const float*)d_in[7];
    const float* bro = (const float*)d_in[8];
    const int* ei    = (const int*)d_in[9];
    const int* batch = (const int*)d_in[10];

    int N = in_sizes[0] / 64;
    int E = in_sizes[9] / 2;
    int G = out_size;

    char* ws = (char*)d_ws;
    size_t off = 0;
    auto carve = [&](size_t bytes) {
        void* p = ws + off;
        off += (bytes + 255) & ~(size_t)255;
        return p;
    };
    int*   cursor = (int*)carve((size_t)N * 4);
    int*   csr    = (int*)carve((size_t)N * MAXDEG * 4);
    float* y      = (float*)carve((size_t)N * 64 * 4);
    float* z      = (float*)carve((size_t)N * 64 * 4);
    float* h      = (float*)carve((size_t)N * 64 * 4);
    float* pool   = (float*)carve((size_t)G * 4);

    hipMemsetAsync(cursor, 0, (size_t)N * 4, stream);
    hipMemsetAsync(pool, 0, (size_t)G * 4, stream);

    k_fill_csr<<<(E + 255) / 256, 256, 0, stream>>>(ei, E, cursor, csr);
    k_gemm<<<(N + 63) / 64, 256, 0, stream>>>(x, Wl1, Wr1, bl1, y, z, N);
    k_gather_l1<<<(N + 15) / 16, 256, 0, stream>>>(y, z, cursor, csr, h, N);
    k_gemm<<<(N + 63) / 64, 256, 0, stream>>>(h, Wl2, Wr2, bl2, y, z, N);
    k_gather_l2<<<(N + 15) / 16, 256, 0, stream>>>(y, z, cursor, csr, batch, Wro, pool, N);
    k_final<<<(G + 255) / 256, 256, 0, stream>>>(pool, batch, bro, (float*)d_out, N, G);
}

// Round 3
// 327.043 us; speedup vs baseline: 2.0361x; 1.9899x over previous
//
#include <hip/hip_runtime.h>

#define MAXDEG 64

__device__ __forceinline__ float4 f4add(float4 a, float4 b) {
    return make_float4(a.x + b.x, a.y + b.y, a.z + b.z, a.w + b.w);
}

// Build per-dst edge lists (bucketed CSR, cap MAXDEG slots/node).
__global__ __launch_bounds__(256) void k_fill_csr(const int* __restrict__ ei, int E,
                                                  int* __restrict__ cursor, int* __restrict__ csr) {
    int e = blockIdx.x * 256 + threadIdx.x;
    if (e >= E) return;
    int src = ei[e];
    int dst = ei[E + e];
    int slot = atomicAdd(&cursor[dst], 1);
    if (slot < MAXDEG) csr[(size_t)dst * MAXDEG + slot] = src;
}

// Pad each node's list to a multiple of 16 with sentinel index n (row n of y is zeroed).
__global__ __launch_bounds__(256) void k_pad(const int* __restrict__ cursor, int* __restrict__ csr,
                                             float* __restrict__ y, int n) {
    if (blockIdx.x == 0 && threadIdx.x < 64) y[(size_t)n * 64 + threadIdx.x] = 0.f;
    int i = blockIdx.x * 256 + threadIdx.x;
    if (i >= n) return;
    int d = cursor[i];
    int dc = d > MAXDEG ? MAXDEG : d;
    int dcp = (dc + 15) & ~15;
    int* p = &csr[(size_t)i * MAXDEG];
    for (int e = dc; e < dcp; ++e) p[e] = n;
}

// Y = X @ Wa ; Z = X @ Wb + bias.  X: n x 64, Wa/Wb: 64x64 row-major [j][k].
__global__ __launch_bounds__(256) void k_gemm(const float* __restrict__ X,
                                              const float* __restrict__ Wa,
                                              const float* __restrict__ Wb,
                                              const float* __restrict__ bias,
                                              float* __restrict__ Y, float* __restrict__ Z, int n) {
    __shared__ float XsT[64][68];
    __shared__ float Wc[64][128];
    int tid = threadIdx.x;
    int n0 = blockIdx.x * 64;

    for (int i = tid; i < 64 * 64; i += 256) {
        int j = i >> 6, k = i & 63;
        Wc[j][k]      = Wa[i];
        Wc[j][64 + k] = Wb[i];
    }
    for (int i = tid; i < 64 * 64; i += 256) {
        int r = i >> 6, c = i & 63;
        int nn = n0 + r;
        XsT[c][r] = (nn < n) ? X[(size_t)nn * 64 + c] : 0.f;
    }
    __syncthreads();

    int tx = tid & 15, ty = tid >> 4;
    float acc[4][8];
#pragma unroll
    for (int u = 0; u < 4; ++u)
#pragma unroll
        for (int v = 0; v < 8; ++v) acc[u][v] = 0.f;

    for (int j = 0; j < 64; ++j) {
        float4 xv = *(const float4*)&XsT[j][ty * 4];
        float4 wa = *(const float4*)&Wc[j][tx * 4];
        float4 wb = *(const float4*)&Wc[j][64 + tx * 4];
        float xs[4] = {xv.x, xv.y, xv.z, xv.w};
        float ws[8] = {wa.x, wa.y, wa.z, wa.w, wb.x, wb.y, wb.z, wb.w};
#pragma unroll
        for (int u = 0; u < 4; ++u)
#pragma unroll
            for (int v = 0; v < 8; ++v) acc[u][v] += xs[u] * ws[v];
    }

    float4 bv = *(const float4*)&bias[tx * 4];
#pragma unroll
    for (int u = 0; u < 4; ++u) {
        int nn = n0 + ty * 4 + u;
        if (nn < n) {
            *(float4*)&Y[(size_t)nn * 64 + tx * 4] =
                make_float4(acc[u][0], acc[u][1], acc[u][2], acc[u][3]);
            *(float4*)&Z[(size_t)nn * 64 + tx * 4] =
                make_float4(acc[u][4] + bv.x, acc[u][5] + bv.y, acc[u][6] + bv.z, acc[u][7] + bv.w);
        }
    }
}

// Gather core: 4 nodes per wave, 16 lanes per node, float4 per lane.
// CSR lists padded to multiple of 16 with sentinel (zero) rows: uniform
// 16-row batches, 16 row-loads in flight per group.
#define GATHER_CORE(ACC_DONE)                                                        \
    int t = threadIdx.x;                                                             \
    int lane = t & 63;                                                               \
    int g = lane >> 4, q = lane & 15;                                                \
    int node = blockIdx.x * 16 + (t >> 6) * 4 + g;                                   \
    if (node >= n) return;                                                           \
    int d = deg[node];                                                               \
    int dc = d > MAXDEG ? MAXDEG : d;                                                \
    int dcp = (dc + 15) & ~15;                                                       \
    const int* lst = &csr[(size_t)node * MAXDEG];                                    \
    float4 z = *(const float4*)&Z[(size_t)node * 64 + q * 4];                        \
    float4 acc = make_float4(0.f, 0.f, 0.f, 0.f);                                    \
    for (int e = 0; e < dcp; e += 16) {                                              \
        int4 i0 = *(const int4*)&lst[e];                                             \
        int4 i1 = *(const int4*)&lst[e + 4];                                         \
        int4 i2 = *(const int4*)&lst[e + 8];                                         \
        int4 i3 = *(const int4*)&lst[e + 12];                                        \
        float4 a0 = *(const float4*)&Y[(size_t)i0.x * 64 + q * 4];                   \
        float4 a1 = *(const float4*)&Y[(size_t)i0.y * 64 + q * 4];                   \
        float4 a2 = *(const float4*)&Y[(size_t)i0.z * 64 + q * 4];                   \
        float4 a3 = *(const float4*)&Y[(size_t)i0.w * 64 + q * 4];                   \
        float4 a4 = *(const float4*)&Y[(size_t)i1.x * 64 + q * 4];                   \
        float4 a5 = *(const float4*)&Y[(size_t)i1.y * 64 + q * 4];                   \
        float4 a6 = *(const float4*)&Y[(size_t)i1.z * 64 + q * 4];                   \
        float4 a7 = *(const float4*)&Y[(size_t)i1.w * 64 + q * 4];                   \
        float4 b0 = *(const float4*)&Y[(size_t)i2.x * 64 + q * 4];                   \
        float4 b1 = *(const float4*)&Y[(size_t)i2.y * 64 + q * 4];                   \
        float4 b2 = *(const float4*)&Y[(size_t)i2.z * 64 + q * 4];                   \
        float4 b3 = *(const float4*)&Y[(size_t)i2.w * 64 + q * 4];                   \
        float4 b4 = *(const float4*)&Y[(size_t)i3.x * 64 + q * 4];                   \
        float4 b5 = *(const float4*)&Y[(size_t)i3.y * 64 + q * 4];                   \
        float4 b6 = *(const float4*)&Y[(size_t)i3.z * 64 + q * 4];                   \
        float4 b7 = *(const float4*)&Y[(size_t)i3.w * 64 + q * 4];                   \
        acc = f4add(acc, f4add(f4add(f4add(a0, a1), f4add(a2, a3)),                  \
                               f4add(f4add(a4, a5), f4add(a6, a7))));                \
        acc = f4add(acc, f4add(f4add(f4add(b0, b1), f4add(b2, b3)),                  \
                               f4add(f4add(b4, b5), f4add(b6, b7))));                \
    }                                                                                \
    float dd = (float)(d > 1 ? d : 1);                                               \
    float4 v;                                                                        \
    v.x = acc.x / dd + z.x;                                                          \
    v.y = acc.y / dd + z.y;                                                          \
    v.z = acc.z / dd + z.z;                                                          \
    v.w = acc.w / dd + z.w;                                                          \
    v.x = v.x > 0.f ? v.x : 0.f;                                                     \
    v.y = v.y > 0.f ? v.y : 0.f;                                                     \
    v.z = v.z > 0.f ? v.z : 0.f;                                                     \
    v.w = v.w > 0.f ? v.w : 0.f;                                                     \
    ACC_DONE

__global__ __launch_bounds__(256) void k_gather_l1(const float* __restrict__ Y,
                                                   const float* __restrict__ Z,
                                                   const int* __restrict__ deg,
                                                   const int* __restrict__ csr,
                                                   float* __restrict__ H, int n) {
    GATHER_CORE({ *(float4*)&H[(size_t)node * 64 + q * 4] = v; })
}

// Layer-2 gather fused with readout dot; writes one scalar per node (no atomics).
__global__ __launch_bounds__(256) void k_gather_l2(const float* __restrict__ Y,
                                                   const float* __restrict__ Z,
                                                   const int* __restrict__ deg,
                                                   const int* __restrict__ csr,
                                                   const float* __restrict__ Wro,
                                                   float* __restrict__ r, int n) {
    GATHER_CORE({
        float4 w = *(const float4*)&Wro[q * 4];
        float s = v.x * w.x + v.y * w.y + v.z * w.z + v.w * w.w;
        s += __shfl_xor(s, 1, 16);
        s += __shfl_xor(s, 2, 16);
        s += __shfl_xor(s, 4, 16);
        s += __shfl_xor(s, 8, 16);
        if (q == 0) r[node] = s;
    })
}

// One block per graph: mean of r over the graph's contiguous node range + bro.
__global__ __launch_bounds__(256) void k_pool(const float* __restrict__ r,
                                              const int* __restrict__ batch,
                                              const float* __restrict__ bro,
                                              float* __restrict__ out, int n) {
    __shared__ float wsum[4];
    int gidx = blockIdx.x;
    int tid = threadIdx.x;
    // lower bounds of gidx and gidx+1 in sorted batch
    int lo = 0, hi = n;
    while (lo < hi) { int m = (lo + hi) >> 1; if (batch[m] < gidx) lo = m + 1; else hi = m; }
    int lb = lo;
    lo = 0; hi = n;
    while (lo < hi) { int m = (lo + hi) >> 1; if (batch[m] < gidx + 1) lo = m + 1; else hi = m; }
    int ub = lo;
    float s = 0.f;
    for (int i = lb + tid; i < ub; i += 256) s += r[i];
#pragma unroll
    for (int off = 32; off; off >>= 1) s += __shfl_xor(s, off, 64);
    if ((tid & 63) == 0) wsum[tid >> 6] = s;
    __syncthreads();
    if (tid == 0) {
        float tot = wsum[0] + wsum[1] + wsum[2] + wsum[3];
        int c = ub - lb;
        out[gidx] = tot / (float)(c > 1 ? c : 1) + bro[0];
    }
}

extern "C" void kernel_launch(void* const* d_in, const int* in_sizes, int n_in,
                              void* d_out, int out_size, void* d_ws, size_t ws_size,
                              hipStream_t stream) {
    const float* x   = (const float*)d_in[0];
    const float* Wl1 = (const float*)d_in[1];
    const float* bl1 = (const float*)d_in[2];
    const float* Wr1 = (const float*)d_in[3];
    const float* Wl2 = (const float*)d_in[4];
    const float* bl2 = (const float*)d_in[5];
    const float* Wr2 = (const float*)d_in[6];
    const float* Wro = (const float*)d_in[7];
    const float* bro = (const float*)d_in[8];
    const int* ei    = (const int*)d_in[9];
    const int* batch = (const int*)d_in[10];

    int N = in_sizes[0] / 64;
    int E = in_sizes[9] / 2;
    int G = out_size;

    char* ws = (char*)d_ws;
    size_t off = 0;
    auto carve = [&](size_t bytes) {
        void* p = ws + off;
        off += (bytes + 255) & ~(size_t)255;
        return p;
    };
    int*   cursor = (int*)carve((size_t)N * 4);
    int*   csr    = (int*)carve((size_t)N * MAXDEG * 4);
    float* y      = (float*)carve((size_t)(N + 1) * 64 * 4);  // +1 sentinel zero row
    float* z      = (float*)carve((size_t)N * 64 * 4);
    float* h      = (float*)carve((size_t)N * 64 * 4);
    float* r      = (float*)carve((size_t)N * 4);

    hipMemsetAsync(cursor, 0, (size_t)N * 4, stream);

    k_fill_csr<<<(E + 255) / 256, 256, 0, stream>>>(ei, E, cursor, csr);
    k_pad<<<(N + 255) / 256, 256, 0, stream>>>(cursor, csr, y, N);
    k_gemm<<<(N + 63) / 64, 256, 0, stream>>>(x, Wl1, Wr1, bl1, y, z, N);
    k_gather_l1<<<(N + 15) / 16, 256, 0, stream>>>(y, z, cursor, csr, h, N);
    k_gemm<<<(N + 63) / 64, 256, 0, stream>>>(h, Wl2, Wr2, bl2, y, z, N);
    k_gather_l2<<<(N + 15) / 16, 256, 0, stream>>>(y, z, cursor, csr, Wro, r, N);
    k_pool<<<G, 256, 0, stream>>>(r, batch, bro, (float*)d_out, N);
}

// Round 4
// 302.868 us; speedup vs baseline: 2.1987x; 1.0798x over previous
//
#include <hip/hip_runtime.h>

#define MAXDEG 64
#define CHUNK 12288
#define NBMAX 256   // buckets = ceil(N/512); N<=131072 (src must fit 17 bits)

__device__ __forceinline__ float4 f4add(float4 a, float4 b) {
    return make_float4(a.x + b.x, a.y + b.y, a.z + b.z, a.w + b.w);
}

// ---- fill stage 1: exact histogram of dst>>9 ----
__global__ __launch_bounds__(256) void k_hist(const int* __restrict__ ei, int E, int NB,
                                              int* __restrict__ ghist) {
    __shared__ int hist[NBMAX];
    for (int b = threadIdx.x; b < NB; b += 256) hist[b] = 0;
    __syncthreads();
    int stride = gridDim.x * 256;
    for (int e = blockIdx.x * 256 + threadIdx.x; e < E; e += stride)
        atomicAdd(&hist[((const unsigned*)ei)[E + e] >> 9], 1);
    __syncthreads();
    for (int b = threadIdx.x; b < NB; b += 256) {
        int h = hist[b];
        if (h) atomicAdd(&ghist[b], h);
    }
}

// ---- fill stage 2: exclusive scan -> bucket bases ----
__global__ void k_scan(const int* __restrict__ ghist, int NB,
                       int* __restrict__ base, int* __restrict__ gcur) {
    if (threadIdx.x == 0) {
        int run = 0;
        for (int b = 0; b < NB; ++b) { base[b] = run; gcur[b] = run; run += ghist[b]; }
    }
}

// ---- fill stage 3: LDS-staged binning, coalesced flush of packed edges ----
__global__ __launch_bounds__(256) void k_binA(const int* __restrict__ ei, int E, int NB,
                                              int* __restrict__ gcur,
                                              unsigned* __restrict__ ebuf) {
    __shared__ unsigned stage[CHUNK];        // 48KB
    __shared__ unsigned char sbkt[CHUNK];    // 12KB
    __shared__ int hist[NBMAX];              // doubles as running cursor
    __shared__ int lofs[NBMAX];
    __shared__ int gofs[NBMAX];
    int tid = threadIdx.x;
    int c0 = blockIdx.x * CHUNK;
    int cend = min(c0 + CHUNK, E);
    for (int b = tid; b < NB; b += 256) hist[b] = 0;
    __syncthreads();
    for (int e = c0 + tid; e < cend; e += 256)
        atomicAdd(&hist[((const unsigned*)ei)[E + e] >> 9], 1);
    __syncthreads();
    if (tid == 0) {
        int run = 0;
        for (int b = 0; b < NB; ++b) { lofs[b] = run; run += hist[b]; }
    }
    __syncthreads();
    for (int b = tid; b < NB; b += 256) {
        gofs[b] = atomicAdd(&gcur[b], hist[b]);   // reserve global run
        hist[b] = lofs[b];                        // reinit as local cursor
    }
    __syncthreads();
    for (int e = c0 + tid; e < cend; e += 256) {
        unsigned dst = ((const unsigned*)ei)[E + e];
        unsigned src = ((const unsigned*)ei)[e];
        int b = dst >> 9;
        int p = atomicAdd(&hist[b], 1);
        stage[p] = ((dst & 511u) << 17) | src;
        sbkt[p] = (unsigned char)b;
    }
    __syncthreads();
    int m = cend - c0;
    for (int i = tid; i < m; i += 256) {
        int b = sbkt[i];
        ebuf[gofs[b] + (i - lofs[b])] = stage[i];
    }
}

// ---- fill stage 4: per-bucket CSR scatter (128KB window, L2-local) ----
__global__ __launch_bounds__(256) void k_binB(const unsigned* __restrict__ ebuf,
                                              const int* __restrict__ base,
                                              const int* __restrict__ ghist,
                                              int* __restrict__ cursor,
                                              int* __restrict__ csr) {
    int b = blockIdx.x;
    int lo = base[b], m = ghist[b];
    int node0 = b << 9;
    for (int i = threadIdx.x; i < m; i += 256) {
        unsigned v = ebuf[lo + i];
        int node = node0 + (int)(v >> 17);
        int src  = (int)(v & 0x1FFFFu);
        int slot = atomicAdd(&cursor[node], 1);
        if (slot < MAXDEG) csr[(size_t)node * MAXDEG + slot] = src;
    }
}

// Pad each node's list to a multiple of 16 with sentinel index n (row n of y is zeroed).
__global__ __launch_bounds__(256) void k_pad(const int* __restrict__ cursor, int* __restrict__ csr,
                                             float* __restrict__ y, int n) {
    if (blockIdx.x == 0 && threadIdx.x < 64) y[(size_t)n * 64 + threadIdx.x] = 0.f;
    int i = blockIdx.x * 256 + threadIdx.x;
    if (i >= n) return;
    int d = cursor[i];
    int dc = d > MAXDEG ? MAXDEG : d;
    int dcp = (dc + 15) & ~15;
    int* p = &csr[(size_t)i * MAXDEG];
    for (int e = dc; e < dcp; ++e) p[e] = n;
}

// Y = X @ Wa ; Z = X @ Wb + bias.  X: n x 64, Wa/Wb: 64x64 row-major [j][k].
__global__ __launch_bounds__(256) void k_gemm(const float* __restrict__ X,
                                              const float* __restrict__ Wa,
                                              const float* __restrict__ Wb,
                                              const float* __restrict__ bias,
                                              float* __restrict__ Y, float* __restrict__ Z, int n) {
    __shared__ float XsT[64][68];
    __shared__ float Wc[64][128];
    int tid = threadIdx.x;
    int n0 = blockIdx.x * 64;

    for (int i = tid; i < 64 * 64; i += 256) {
        int j = i >> 6, k = i & 63;
        Wc[j][k]      = Wa[i];
        Wc[j][64 + k] = Wb[i];
    }
    for (int i = tid; i < 64 * 64; i += 256) {
        int r = i >> 6, c = i & 63;
        int nn = n0 + r;
        XsT[c][r] = (nn < n) ? X[(size_t)nn * 64 + c] : 0.f;
    }
    __syncthreads();

    int tx = tid & 15, ty = tid >> 4;
    float acc[4][8];
#pragma unroll
    for (int u = 0; u < 4; ++u)
#pragma unroll
        for (int v = 0; v < 8; ++v) acc[u][v] = 0.f;

    for (int j = 0; j < 64; ++j) {
        float4 xv = *(const float4*)&XsT[j][ty * 4];
        float4 wa = *(const float4*)&Wc[j][tx * 4];
        float4 wb = *(const float4*)&Wc[j][64 + tx * 4];
        float xs[4] = {xv.x, xv.y, xv.z, xv.w};
        float ws[8] = {wa.x, wa.y, wa.z, wa.w, wb.x, wb.y, wb.z, wb.w};
#pragma unroll
        for (int u = 0; u < 4; ++u)
#pragma unroll
            for (int v = 0; v < 8; ++v) acc[u][v] += xs[u] * ws[v];
    }

    float4 bv = *(const float4*)&bias[tx * 4];
#pragma unroll
    for (int u = 0; u < 4; ++u) {
        int nn = n0 + ty * 4 + u;
        if (nn < n) {
            *(float4*)&Y[(size_t)nn * 64 + tx * 4] =
                make_float4(acc[u][0], acc[u][1], acc[u][2], acc[u][3]);
            *(float4*)&Z[(size_t)nn * 64 + tx * 4] =
                make_float4(acc[u][4] + bv.x, acc[u][5] + bv.y, acc[u][6] + bv.z, acc[u][7] + bv.w);
        }
    }
}

// Gather core: 4 nodes per wave, 16 lanes per node, float4 per lane.
// CSR lists padded to multiple of 16 with sentinel (zero) rows.
#define GATHER_CORE(ACC_DONE)                                                        \
    int t = threadIdx.x;                                                             \
    int lane = t & 63;                                                               \
    int g = lane >> 4, q = lane & 15;                                                \
    int node = blockIdx.x * 16 + (t >> 6) * 4 + g;                                   \
    if (node >= n) return;                                                           \
    int d = deg[node];                                                               \
    int dc = d > MAXDEG ? MAXDEG : d;                                                \
    int dcp = (dc + 15) & ~15;                                                       \
    const int* lst = &csr[(size_t)node * MAXDEG];                                    \
    float4 z = *(const float4*)&Z[(size_t)node * 64 + q * 4];                        \
    float4 acc = make_float4(0.f, 0.f, 0.f, 0.f);                                    \
    for (int e = 0; e < dcp; e += 16) {                                              \
        int4 i0 = *(const int4*)&lst[e];                                             \
        int4 i1 = *(const int4*)&lst[e + 4];                                         \
        int4 i2 = *(const int4*)&lst[e + 8];                                         \
        int4 i3 = *(const int4*)&lst[e + 12];                                        \
        float4 a0 = *(const float4*)&Y[(size_t)i0.x * 64 + q * 4];                   \
        float4 a1 = *(const float4*)&Y[(size_t)i0.y * 64 + q * 4];                   \
        float4 a2 = *(const float4*)&Y[(size_t)i0.z * 64 + q * 4];                   \
        float4 a3 = *(const float4*)&Y[(size_t)i0.w * 64 + q * 4];                   \
        float4 a4 = *(const float4*)&Y[(size_t)i1.x * 64 + q * 4];                   \
        float4 a5 = *(const float4*)&Y[(size_t)i1.y * 64 + q * 4];                   \
        float4 a6 = *(const float4*)&Y[(size_t)i1.z * 64 + q * 4];                   \
        float4 a7 = *(const float4*)&Y[(size_t)i1.w * 64 + q * 4];                   \
        float4 b0 = *(const float4*)&Y[(size_t)i2.x * 64 + q * 4];                   \
        float4 b1 = *(const float4*)&Y[(size_t)i2.y * 64 + q * 4];                   \
        float4 b2 = *(const float4*)&Y[(size_t)i2.z * 64 + q * 4];                   \
        float4 b3 = *(const float4*)&Y[(size_t)i2.w * 64 + q * 4];                   \
        float4 b4 = *(const float4*)&Y[(size_t)i3.x * 64 + q * 4];                   \
        float4 b5 = *(const float4*)&Y[(size_t)i3.y * 64 + q * 4];                   \
        float4 b6 = *(const float4*)&Y[(size_t)i3.z * 64 + q * 4];                   \
        float4 b7 = *(const float4*)&Y[(size_t)i3.w * 64 + q * 4];                   \
        acc = f4add(acc, f4add(f4add(f4add(a0, a1), f4add(a2, a3)),                  \
                               f4add(f4add(a4, a5), f4add(a6, a7))));                \
        acc = f4add(acc, f4add(f4add(f4add(b0, b1), f4add(b2, b3)),                  \
                               f4add(f4add(b4, b5), f4add(b6, b7))));                \
    }                                                                                \
    float dd = (float)(d > 1 ? d : 1);                                               \
    float4 v;                                                                        \
    v.x = acc.x / dd + z.x;                                                          \
    v.y = acc.y / dd + z.y;                                                          \
    v.z = acc.z / dd + z.z;                                                          \
    v.w = acc.w / dd + z.w;                                                          \
    v.x = v.x > 0.f ? v.x : 0.f;                                                     \
    v.y = v.y > 0.f ? v.y : 0.f;                                                     \
    v.z = v.z > 0.f ? v.z : 0.f;                                                     \
    v.w = v.w > 0.f ? v.w : 0.f;                                                     \
    ACC_DONE

__global__ __launch_bounds__(256) void k_gather_l1(const float* __restrict__ Y,
                                                   const float* __restrict__ Z,
                                                   const int* __restrict__ deg,
                                                   const int* __restrict__ csr,
                                                   float* __restrict__ H, int n) {
    GATHER_CORE({ *(float4*)&H[(size_t)node * 64 + q * 4] = v; })
}

// Layer-2 gather fused with readout dot; writes one scalar per node (no atomics).
__global__ __launch_bounds__(256) void k_gather_l2(const float* __restrict__ Y,
                                                   const float* __restrict__ Z,
                                                   const int* __restrict__ deg,
                                                   const int* __restrict__ csr,
                                                   const float* __restrict__ Wro,
                                                   float* __restrict__ r, int n) {
    GATHER_CORE({
        float4 w = *(const float4*)&Wro[q * 4];
        float s = v.x * w.x + v.y * w.y + v.z * w.z + v.w * w.w;
        s += __shfl_xor(s, 1, 16);
        s += __shfl_xor(s, 2, 16);
        s += __shfl_xor(s, 4, 16);
        s += __shfl_xor(s, 8, 16);
        if (q == 0) r[node] = s;
    })
}

// One block per graph: mean of r over the graph's contiguous node range + bro.
__global__ __launch_bounds__(256) void k_pool(const float* __restrict__ r,
                                              const int* __restrict__ batch,
                                              const float* __restrict__ bro,
                                              float* __restrict__ out, int n) {
    __shared__ float wsum[4];
    int gidx = blockIdx.x;
    int tid = threadIdx.x;
    int lo = 0, hi = n;
    while (lo < hi) { int m = (lo + hi) >> 1; if (batch[m] < gidx) lo = m + 1; else hi = m; }
    int lb = lo;
    lo = 0; hi = n;
    while (lo < hi) { int m = (lo + hi) >> 1; if (batch[m] < gidx + 1) lo = m + 1; else hi = m; }
    int ub = lo;
    float s = 0.f;
    for (int i = lb + tid; i < ub; i += 256) s += r[i];
#pragma unroll
    for (int off = 32; off; off >>= 1) s += __shfl_xor(s, off, 64);
    if ((tid & 63) == 0) wsum[tid >> 6] = s;
    __syncthreads();
    if (tid == 0) {
        float tot = wsum[0] + wsum[1] + wsum[2] + wsum[3];
        int c = ub - lb;
        out[gidx] = tot / (float)(c > 1 ? c : 1) + bro[0];
    }
}

extern "C" void kernel_launch(void* const* d_in, const int* in_sizes, int n_in,
                              void* d_out, int out_size, void* d_ws, size_t ws_size,
                              hipStream_t stream) {
    const float* x   = (const float*)d_in[0];
    const float* Wl1 = (const float*)d_in[1];
    const float* bl1 = (const float*)d_in[2];
    const float* Wr1 = (const float*)d_in[3];
    const float* Wl2 = (const float*)d_in[4];
    const float* bl2 = (const float*)d_in[5];
    const float* Wr2 = (const float*)d_in[6];
    const float* Wro = (const float*)d_in[7];
    const float* bro = (const float*)d_in[8];
    const int* ei    = (const int*)d_in[9];
    const int* batch = (const int*)d_in[10];

    int N = in_sizes[0] / 64;
    int E = in_sizes[9] / 2;
    int G = out_size;
    int NB = (N + 511) >> 9;   // buckets of 512 nodes

    char* ws = (char*)d_ws;
    size_t off = 0;
    auto carve = [&](size_t bytes) {
        void* p = ws + off;
        off += (bytes + 255) & ~(size_t)255;
        return p;
    };
    int*      cursor = (int*)carve((size_t)N * 4);
    int*      csr    = (int*)carve((size_t)N * MAXDEG * 4);
    float*    y      = (float*)carve((size_t)(N + 1) * 64 * 4);  // +1 sentinel zero row
    float*    z      = (float*)carve((size_t)N * 64 * 4);
    float*    h      = (float*)carve((size_t)N * 64 * 4);
    float*    r      = (float*)carve((size_t)N * 4);
    int*      ghist  = (int*)carve((size_t)NB * 4);
    int*      base   = (int*)carve((size_t)NB * 4);
    int*      gcur   = (int*)carve((size_t)NB * 4);
    unsigned* ebuf   = (unsigned*)carve((size_t)E * 4);

    hipMemsetAsync(cursor, 0, (size_t)N * 4, stream);
    hipMemsetAsync(ghist, 0, (size_t)NB * 4, stream);

    k_hist<<<256, 256, 0, stream>>>(ei, E, NB, ghist);
    k_scan<<<1, 64, 0, stream>>>(ghist, NB, base, gcur);
    k_binA<<<(E + CHUNK - 1) / CHUNK, 256, 0, stream>>>(ei, E, NB, gcur, ebuf);
    k_binB<<<NB, 256, 0, stream>>>(ebuf, base, ghist, cursor, csr);
    k_pad<<<(N + 255) / 256, 256, 0, stream>>>(cursor, csr, y, N);
    k_gemm<<<(N + 63) / 64, 256, 0, stream>>>(x, Wl1, Wr1, bl1, y, z, N);
    k_gather_l1<<<(N + 15) / 16, 256, 0, stream>>>(y, z, cursor, csr, h, N);
    k_gemm<<<(N + 63) / 64, 256, 0, stream>>>(h, Wl2, Wr2, bl2, y, z, N);
    k_gather_l2<<<(N + 15) / 16, 256, 0, stream>>>(y, z, cursor, csr, Wro, r, N);
    k_pool<<<G, 256, 0, stream>>>(r, batch, bro, (float*)d_out, N);
}

// Round 5
// 277.724 us; speedup vs baseline: 2.3977x; 1.0905x over previous
//
#include <hip/hip_runtime.h>

#define MAXDEG 64
#define CHUNK 12288
#define NBMAX 256   // buckets = ceil(N/512); N<=131072 (src must fit 17 bits)

typedef unsigned short u16;

__device__ __forceinline__ float4 f4add(float4 a, float4 b) {
    return make_float4(a.x + b.x, a.y + b.y, a.z + b.z, a.w + b.w);
}

__device__ __forceinline__ u16 f2b(float f) {   // fp32 -> bf16 rne
    unsigned u = __float_as_uint(f);
    u += 0x7fffu + ((u >> 16) & 1u);
    return (u16)(u >> 16);
}

// acc += bf16x4 row fragment (w = 4 packed bf16)
__device__ __forceinline__ void bacc(float4& acc, uint2 w) {
    acc.x += __uint_as_float(w.x << 16);
    acc.y += __uint_as_float(w.x & 0xffff0000u);
    acc.z += __uint_as_float(w.y << 16);
    acc.w += __uint_as_float(w.y & 0xffff0000u);
}

// ---- fill stage 1: per-chunk histogram of dst>>9 ----
__global__ __launch_bounds__(256) void k_chunkhist(const int* __restrict__ ei, int E, int NB, int NC,
                                                   int* __restrict__ chist) {
    __shared__ int hist[NBMAX];
    for (int i = threadIdx.x; i < NB; i += 256) hist[i] = 0;
    __syncthreads();
    int c0 = blockIdx.x * CHUNK, cend = min(c0 + CHUNK, E);
    for (int e = c0 + threadIdx.x; e < cend; e += 256)
        atomicAdd(&hist[((const unsigned*)ei)[E + e] >> 9], 1);
    __syncthreads();
    for (int i = threadIdx.x; i < NB; i += 256) chist[(size_t)i * NC + blockIdx.x] = hist[i];
}

// ---- fill stage 2: column-prefix per bucket + bucket bases (parallel over buckets) ----
__global__ __launch_bounds__(256) void k_scan2(int* __restrict__ chist, int NB, int NC,
                                               int* __restrict__ base, int* __restrict__ ghist) {
    __shared__ int tots[NBMAX];
    __shared__ int bs[NBMAX];
    int b = threadIdx.x;
    if (b < NB) {
        int run = 0;
        int* row = &chist[(size_t)b * NC];
        for (int c = 0; c < NC; ++c) { int v = row[c]; row[c] = run; run += v; }
        tots[b] = run;
    }
    __syncthreads();
    if (threadIdx.x == 0) {
        int run = 0;
        for (int i = 0; i < NB; ++i) { bs[i] = run; run += tots[i]; }
    }
    __syncthreads();
    if (b < NB) { base[b] = bs[b]; ghist[b] = tots[b]; }
}

// ---- fill stage 3: single-pass LDS-staged binning, coalesced flush ----
__global__ __launch_bounds__(256) void k_binA(const int* __restrict__ ei, int E, int NB, int NC,
                                              const int* __restrict__ chist,
                                              const int* __restrict__ base,
                                              const int* __restrict__ ghist,
                                              unsigned* __restrict__ ebuf) {
    __shared__ unsigned stage[CHUNK];        // 48KB
    __shared__ unsigned char sbkt[CHUNK];    // 12KB
    __shared__ int cur[NBMAX];
    __shared__ int lofs[NBMAX];
    __shared__ int gofs[NBMAX];
    __shared__ int hcnt[NBMAX];
    int tid = threadIdx.x, c = blockIdx.x;
    int c0 = c * CHUNK, cend = min(c0 + CHUNK, E);
    if (tid < NB) {
        int g0 = chist[(size_t)tid * NC + c];
        int g1 = (c == NC - 1) ? ghist[tid] : chist[(size_t)tid * NC + c + 1];
        hcnt[tid] = g1 - g0;
        gofs[tid] = base[tid] + g0;
    }
    __syncthreads();
    if (tid == 0) {
        int run = 0;
        for (int b = 0; b < NB; ++b) { lofs[b] = run; cur[b] = run; run += hcnt[b]; }
    }
    __syncthreads();
    for (int e = c0 + tid; e < cend; e += 256) {
        unsigned dst = ((const unsigned*)ei)[E + e];
        unsigned src = ((const unsigned*)ei)[e];
        int b = dst >> 9;
        int p = atomicAdd(&cur[b], 1);
        stage[p] = ((dst & 511u) << 17) | src;
        sbkt[p] = (unsigned char)b;
    }
    __syncthreads();
    int m = cend - c0;
    for (int i = tid; i < m; i += 256) {
        int b = sbkt[i];
        ebuf[gofs[b] + (i - lofs[b])] = stage[i];
    }
}

// ---- fill stage 4: per-bucket CSR scatter (128KB window, L2-local) ----
__global__ __launch_bounds__(256) void k_binB(const unsigned* __restrict__ ebuf,
                                              const int* __restrict__ base,
                                              const int* __restrict__ ghist,
                                              int* __restrict__ cursor,
                                              int* __restrict__ csr) {
    int b = blockIdx.x;
    int lo = base[b], m = ghist[b];
    int node0 = b << 9;
    for (int i = threadIdx.x; i < m; i += 256) {
        unsigned v = ebuf[lo + i];
        int node = node0 + (int)(v >> 17);
        int src  = (int)(v & 0x1FFFFu);
        int slot = atomicAdd(&cursor[node], 1);
        if (slot < MAXDEG) csr[(size_t)node * MAXDEG + slot] = src;
    }
}

// Pad lists to multiple of 16 with sentinel index n; zero bf16 row n of y.
__global__ __launch_bounds__(256) void k_pad(const int* __restrict__ cursor, int* __restrict__ csr,
                                             u16* __restrict__ y, int n) {
    if (blockIdx.x == 0 && threadIdx.x < 32) ((unsigned*)&y[(size_t)n * 64])[threadIdx.x] = 0u;
    int i = blockIdx.x * 256 + threadIdx.x;
    if (i >= n) return;
    int d = cursor[i];
    int dc = d > MAXDEG ? MAXDEG : d;
    int dcp = (dc + 15) & ~15;
    int* p = &csr[(size_t)i * MAXDEG];
    for (int e = dc; e < dcp; ++e) p[e] = n;
}

// Y(bf16) = X @ Wa ; Z(fp32) = X @ Wb + bias.  X: n x 64 fp32, W row-major [j][k].
__global__ __launch_bounds__(256) void k_gemm(const float* __restrict__ X,
                                              const float* __restrict__ Wa,
                                              const float* __restrict__ Wb,
                                              const float* __restrict__ bias,
                                              u16* __restrict__ Y, float* __restrict__ Z, int n) {
    __shared__ float XsT[64][68];
    __shared__ float Wc[64][128];
    int tid = threadIdx.x;
    int n0 = blockIdx.x * 64;

    for (int i = tid; i < 64 * 64; i += 256) {
        int j = i >> 6, k = i & 63;
        Wc[j][k]      = Wa[i];
        Wc[j][64 + k] = Wb[i];
    }
    for (int i = tid; i < 64 * 64; i += 256) {
        int r = i >> 6, c = i & 63;
        int nn = n0 + r;
        XsT[c][r] = (nn < n) ? X[(size_t)nn * 64 + c] : 0.f;
    }
    __syncthreads();

    int tx = tid & 15, ty = tid >> 4;
    float acc[4][8];
#pragma unroll
    for (int u = 0; u < 4; ++u)
#pragma unroll
        for (int v = 0; v < 8; ++v) acc[u][v] = 0.f;

    for (int j = 0; j < 64; ++j) {
        float4 xv = *(const float4*)&XsT[j][ty * 4];
        float4 wa = *(const float4*)&Wc[j][tx * 4];
        float4 wb = *(const float4*)&Wc[j][64 + tx * 4];
        float xs[4] = {xv.x, xv.y, xv.z, xv.w};
        float ws[8] = {wa.x, wa.y, wa.z, wa.w, wb.x, wb.y, wb.z, wb.w};
#pragma unroll
        for (int u = 0; u < 4; ++u)
#pragma unroll
            for (int v = 0; v < 8; ++v) acc[u][v] += xs[u] * ws[v];
    }

    float4 bv = *(const float4*)&bias[tx * 4];
#pragma unroll
    for (int u = 0; u < 4; ++u) {
        int nn = n0 + ty * 4 + u;
        if (nn < n) {
            ushort4 o;
            o.x = f2b(acc[u][0]); o.y = f2b(acc[u][1]);
            o.z = f2b(acc[u][2]); o.w = f2b(acc[u][3]);
            *(ushort4*)&Y[(size_t)nn * 64 + tx * 4] = o;
            *(float4*)&Z[(size_t)nn * 64 + tx * 4] =
                make_float4(acc[u][4] + bv.x, acc[u][5] + bv.y, acc[u][6] + bv.z, acc[u][7] + bv.w);
        }
    }
}

// Gather core: 4 nodes per wave, 16 lanes per node, 4 bf16 cols per lane.
#define GATHER_CORE(ACC_DONE)                                                        \
    int t = threadIdx.x;                                                             \
    int lane = t & 63;                                                               \
    int g = lane >> 4, q = lane & 15;                                                \
    int node = blockIdx.x * 16 + (t >> 6) * 4 + g;                                   \
    if (node >= n) return;                                                           \
    int d = deg[node];                                                               \
    int dc = d > MAXDEG ? MAXDEG : d;                                                \
    int dcp = (dc + 15) & ~15;                                                       \
    const int* lst = &csr[(size_t)node * MAXDEG];                                    \
    float4 z = *(const float4*)&Z[(size_t)node * 64 + q * 4];                        \
    float4 acc = make_float4(0.f, 0.f, 0.f, 0.f);                                    \
    for (int e = 0; e < dcp; e += 16) {                                              \
        int4 i0 = *(const int4*)&lst[e];                                             \
        int4 i1 = *(const int4*)&lst[e + 4];                                         \
        int4 i2 = *(const int4*)&lst[e + 8];                                         \
        int4 i3 = *(const int4*)&lst[e + 12];                                        \
        uint2 a0 = *(const uint2*)&Y[(size_t)i0.x * 64 + q * 4];                     \
        uint2 a1 = *(const uint2*)&Y[(size_t)i0.y * 64 + q * 4];                     \
        uint2 a2 = *(const uint2*)&Y[(size_t)i0.z * 64 + q * 4];                     \
        uint2 a3 = *(const uint2*)&Y[(size_t)i0.w * 64 + q * 4];                     \
        uint2 a4 = *(const uint2*)&Y[(size_t)i1.x * 64 + q * 4];                     \
        uint2 a5 = *(const uint2*)&Y[(size_t)i1.y * 64 + q * 4];                     \
        uint2 a6 = *(const uint2*)&Y[(size_t)i1.z * 64 + q * 4];                     \
        uint2 a7 = *(const uint2*)&Y[(size_t)i1.w * 64 + q * 4];                     \
        uint2 b0 = *(const uint2*)&Y[(size_t)i2.x * 64 + q * 4];                     \
        uint2 b1 = *(const uint2*)&Y[(size_t)i2.y * 64 + q * 4];                     \
        uint2 b2 = *(const uint2*)&Y[(size_t)i2.z * 64 + q * 4];                     \
        uint2 b3 = *(const uint2*)&Y[(size_t)i2.w * 64 + q * 4];                     \
        uint2 b4 = *(const uint2*)&Y[(size_t)i3.x * 64 + q * 4];                     \
        uint2 b5 = *(const uint2*)&Y[(size_t)i3.y * 64 + q * 4];                     \
        uint2 b6 = *(const uint2*)&Y[(size_t)i3.z * 64 + q * 4];                     \
        uint2 b7 = *(const uint2*)&Y[(size_t)i3.w * 64 + q * 4];                     \
        bacc(acc, a0); bacc(acc, a1); bacc(acc, a2); bacc(acc, a3);                  \
        bacc(acc, a4); bacc(acc, a5); bacc(acc, a6); bacc(acc, a7);                  \
        bacc(acc, b0); bacc(acc, b1); bacc(acc, b2); bacc(acc, b3);                  \
        bacc(acc, b4); bacc(acc, b5); bacc(acc, b6); bacc(acc, b7);                  \
    }                                                                                \
    float inv = 1.0f / (float)(d > 1 ? d : 1);                                       \
    float4 v;                                                                        \
    v.x = acc.x * inv + z.x;                                                         \
    v.y = acc.y * inv + z.y;                                                         \
    v.z = acc.z * inv + z.z;                                                         \
    v.w = acc.w * inv + z.w;                                                         \
    v.x = v.x > 0.f ? v.x : 0.f;                                                     \
    v.y = v.y > 0.f ? v.y : 0.f;                                                     \
    v.z = v.z > 0.f ? v.z : 0.f;                                                     \
    v.w = v.w > 0.f ? v.w : 0.f;                                                     \
    ACC_DONE

__global__ __launch_bounds__(256) void k_gather_l1(const u16* __restrict__ Y,
                                                   const float* __restrict__ Z,
                                                   const int* __restrict__ deg,
                                                   const int* __restrict__ csr,
                                                   float* __restrict__ H, int n) {
    GATHER_CORE({ *(float4*)&H[(size_t)node * 64 + q * 4] = v; })
}

// Layer-2 gather fused with readout dot; one scalar per node.
__global__ __launch_bounds__(256) void k_gather_l2(const u16* __restrict__ Y,
                                                   const float* __restrict__ Z,
                                                   const int* __restrict__ deg,
                                                   const int* __restrict__ csr,
                                                   const float* __restrict__ Wro,
                                                   float* __restrict__ r, int n) {
    GATHER_CORE({
        float4 w = *(const float4*)&Wro[q * 4];
        float s = v.x * w.x + v.y * w.y + v.z * w.z + v.w * w.w;
        s += __shfl_xor(s, 1, 16);
        s += __shfl_xor(s, 2, 16);
        s += __shfl_xor(s, 4, 16);
        s += __shfl_xor(s, 8, 16);
        if (q == 0) r[node] = s;
    })
}

// One block per graph: mean of r over the graph's contiguous node range + bro.
__global__ __launch_bounds__(256) void k_pool(const float* __restrict__ r,
                                              const int* __restrict__ batch,
                                              const float* __restrict__ bro,
                                              float* __restrict__ out, int n) {
    __shared__ float wsum[4];
    int gidx = blockIdx.x;
    int tid = threadIdx.x;
    int lo = 0, hi = n;
    while (lo < hi) { int m = (lo + hi) >> 1; if (batch[m] < gidx) lo = m + 1; else hi = m; }
    int lb = lo;
    lo = 0; hi = n;
    while (lo < hi) { int m = (lo + hi) >> 1; if (batch[m] < gidx + 1) lo = m + 1; else hi = m; }
    int ub = lo;
    float s = 0.f;
    for (int i = lb + tid; i < ub; i += 256) s += r[i];
#pragma unroll
    for (int off = 32; off; off >>= 1) s += __shfl_xor(s, off, 64);
    if ((tid & 63) == 0) wsum[tid >> 6] = s;
    __syncthreads();
    if (tid == 0) {
        float tot = wsum[0] + wsum[1] + wsum[2] + wsum[3];
        int c = ub - lb;
        out[gidx] = tot / (float)(c > 1 ? c : 1) + bro[0];
    }
}

extern "C" void kernel_launch(void* const* d_in, const int* in_sizes, int n_in,
                              void* d_out, int out_size, void* d_ws, size_t ws_size,
                              hipStream_t stream) {
    const float* x   = (const float*)d_in[0];
    const float* Wl1 = (const float*)d_in[1];
    const float* bl1 = (const float*)d_in[2];
    const float* Wr1 = (const float*)d_in[3];
    const float* Wl2 = (const float*)d_in[4];
    const float* bl2 = (const float*)d_in[5];
    const float* Wr2 = (const float*)d_in[6];
    const float* Wro = (const float*)d_in[7];
    const float* bro = (const float*)d_in[8];
    const int* ei    = (const int*)d_in[9];
    const int* batch = (const int*)d_in[10];

    int N = in_sizes[0] / 64;
    int E = in_sizes[9] / 2;
    int G = out_size;
    int NB = (N + 511) >> 9;              // buckets of 512 nodes
    int NC = (E + CHUNK - 1) / CHUNK;     // chunks

    char* ws = (char*)d_ws;
    size_t off = 0;
    auto carve = [&](size_t bytes) {
        void* p = ws + off;
        off += (bytes + 255) & ~(size_t)255;
        return p;
    };
    int*      cursor = (int*)carve((size_t)N * 4);
    int*      csr    = (int*)carve((size_t)N * MAXDEG * 4);
    u16*      y      = (u16*)carve((size_t)(N + 1) * 64 * 2);   // bf16 rows, +1 sentinel
    float*    z      = (float*)carve((size_t)N * 64 * 4);
    float*    h      = (float*)carve((size_t)N * 64 * 4);
    float*    r      = (float*)carve((size_t)N * 4);
    int*      ghist  = (int*)carve((size_t)NB * 4);
    int*      base   = (int*)carve((size_t)NB * 4);
    int*      chist  = (int*)carve((size_t)NB * NC * 4);
    unsigned* ebuf   = (unsigned*)carve((size_t)E * 4);

    hipMemsetAsync(cursor, 0, (size_t)N * 4, stream);

    k_chunkhist<<<NC, 256, 0, stream>>>(ei, E, NB, NC, chist);
    k_scan2<<<1, 256, 0, stream>>>(chist, NB, NC, base, ghist);
    k_binA<<<NC, 256, 0, stream>>>(ei, E, NB, NC, chist, base, ghist, ebuf);
    k_binB<<<NB, 256, 0, stream>>>(ebuf, base, ghist, cursor, csr);
    k_pad<<<(N + 255) / 256, 256, 0, stream>>>(cursor, csr, y, N);
    k_gemm<<<(N + 63) / 64, 256, 0, stream>>>(x, Wl1, Wr1, bl1, y, z, N);
    k_gather_l1<<<(N + 15) / 16, 256, 0, stream>>>(y, z, cursor, csr, h, N);
    k_gemm<<<(N + 63) / 64, 256, 0, stream>>>(h, Wl2, Wr2, bl2, y, z, N);
    k_gather_l2<<<(N + 15) / 16, 256, 0, stream>>>(y, z, cursor, csr, Wro, r, N);
    k_pool<<<G, 256, 0, stream>>>(r, batch, bro, (float*)d_out, N);
}

// Round 6
// 201.177 us; speedup vs baseline: 3.3101x; 1.3805x over previous
//
#include <hip/hip_runtime.h>

#define MAXDEG 64
#define CHUNK 12288
#define NBMAX 256   // buckets = ceil(N/512); N<=131072 (src must fit 17 bits)
#define GB 128      // gemm nodes per block

typedef unsigned short u16;

__device__ __forceinline__ u16 f2b(float f) {   // fp32 -> bf16 rne
    unsigned u = __float_as_uint(f);
    u += 0x7fffu + ((u >> 16) & 1u);
    return (u16)(u >> 16);
}

// acc += bf16x4 row fragment (w = 4 packed bf16)
__device__ __forceinline__ void bacc(float4& acc, uint2 w) {
    acc.x += __uint_as_float(w.x << 16);
    acc.y += __uint_as_float(w.x & 0xffff0000u);
    acc.z += __uint_as_float(w.y << 16);
    acc.w += __uint_as_float(w.y & 0xffff0000u);
}

// ---- fill stage 1: per-chunk histogram of dst>>9 ----
__global__ __launch_bounds__(256) void k_chunkhist(const int* __restrict__ ei, int E, int NB, int NC,
                                                   int* __restrict__ chist) {
    __shared__ int hist[NBMAX];
    for (int i = threadIdx.x; i < NB; i += 256) hist[i] = 0;
    __syncthreads();
    int c0 = blockIdx.x * CHUNK, cend = min(c0 + CHUNK, E);
    for (int e = c0 + threadIdx.x; e < cend; e += 256)
        atomicAdd(&hist[((const unsigned*)ei)[E + e] >> 9], 1);
    __syncthreads();
    for (int i = threadIdx.x; i < NB; i += 256) chist[(size_t)i * NC + blockIdx.x] = hist[i];
}

// block-wide exclusive scan helper: input v per thread, returns exclusive prefix; *tot = total
__device__ __forceinline__ int block_exscan(int v, int* wsum, int* tot) {
    int tid = threadIdx.x, lane = tid & 63, wid = tid >> 6;
    int inc = v;
#pragma unroll
    for (int off = 1; off < 64; off <<= 1) {
        int t = __shfl_up(inc, off, 64);
        if (lane >= off) inc += t;
    }
    if (lane == 63) wsum[wid] = inc;
    __syncthreads();
    if (tid == 0) {
        int run = 0;
#pragma unroll
        for (int w = 0; w < 4; ++w) { int t = wsum[w]; wsum[w] = run; run += t; }
        wsum[4] = run;
    }
    __syncthreads();
    inc += wsum[wid];
    if (tot) *tot = wsum[4];
    return inc - v;
}

// ---- fill stage 2a: per-bucket exclusive scan over its NC chunk counts ----
__global__ __launch_bounds__(256) void k_scanA(int* __restrict__ chist, int NB, int NC,
                                               int* __restrict__ ghist) {
    __shared__ int wsum[5];
    int b = blockIdx.x;
    int c = threadIdx.x;
    int* row = &chist[(size_t)b * NC];
    int v = (c < NC) ? row[c] : 0;
    int tot;
    int ex = block_exscan(v, wsum, &tot);
    if (c < NC) row[c] = ex;
    if (c == 0) ghist[b] = tot;
}

// ---- fill stage 2b: exclusive scan of bucket totals -> base; zero y sentinel row ----
__global__ __launch_bounds__(256) void k_scanB(const int* __restrict__ ghist, int NB,
                                               int* __restrict__ base, u16* __restrict__ y, int n) {
    __shared__ int wsum[5];
    int b = threadIdx.x;
    if (b < 32) ((unsigned*)&y[(size_t)n * 64])[b] = 0u;
    int v = (b < NB) ? ghist[b] : 0;
    int ex = block_exscan(v, wsum, 0);
    if (b < NB) base[b] = ex;
}

// ---- fill stage 3: single-pass LDS-staged binning, coalesced flush ----
__global__ __launch_bounds__(256) void k_binA(const int* __restrict__ ei, int E, int NB, int NC,
                                              const int* __restrict__ chist,
                                              const int* __restrict__ base,
                                              const int* __restrict__ ghist,
                                              unsigned* __restrict__ ebuf) {
    __shared__ unsigned stage[CHUNK];        // 48KB
    __shared__ unsigned char sbkt[CHUNK];    // 12KB
    __shared__ int cur[NBMAX];
    __shared__ int lofs[NBMAX];
    __shared__ int gofs[NBMAX];
    __shared__ int hcnt[NBMAX];
    int tid = threadIdx.x, c = blockIdx.x;
    int c0 = c * CHUNK, cend = min(c0 + CHUNK, E);
    if (tid < NB) {
        int g0 = chist[(size_t)tid * NC + c];
        int g1 = (c == NC - 1) ? ghist[tid] : chist[(size_t)tid * NC + c + 1];
        hcnt[tid] = g1 - g0;
        gofs[tid] = base[tid] + g0;
    }
    __syncthreads();
    if (tid == 0) {
        int run = 0;
        for (int b = 0; b < NB; ++b) { lofs[b] = run; cur[b] = run; run += hcnt[b]; }
    }
    __syncthreads();
    for (int e = c0 + tid; e < cend; e += 256) {
        unsigned dst = ((const unsigned*)ei)[E + e];
        unsigned src = ((const unsigned*)ei)[e];
        int b = dst >> 9;
        int p = atomicAdd(&cur[b], 1);
        stage[p] = ((dst & 511u) << 17) | src;
        sbkt[p] = (unsigned char)b;
    }
    __syncthreads();
    int m = cend - c0;
    for (int i = tid; i < m; i += 256) {
        int b = sbkt[i];
        ebuf[gofs[b] + (i - lofs[b])] = stage[i];
    }
}

// ---- fill stage 4: per-bucket CSR scatter (LDS counters) + cursor write + pad ----
__global__ __launch_bounds__(256) void k_binB(const unsigned* __restrict__ ebuf,
                                              const int* __restrict__ base,
                                              const int* __restrict__ ghist,
                                              int* __restrict__ cursor,
                                              int* __restrict__ csr, int n) {
    __shared__ int lcur[512];
    int b = blockIdx.x;
    int tid = threadIdx.x;
    for (int i = tid; i < 512; i += 256) lcur[i] = 0;
    __syncthreads();
    int lo = base[b], m = ghist[b];
    int node0 = b << 9;
    for (int i = tid; i < m; i += 256) {
        unsigned v = ebuf[lo + i];
        int ln   = (int)(v >> 17);
        int src  = (int)(v & 0x1FFFFu);
        int slot = atomicAdd(&lcur[ln], 1);
        if (slot < MAXDEG) csr[(size_t)(node0 + ln) * MAXDEG + slot] = src;
    }
    __syncthreads();
    int nb = min(512, n - node0);
    for (int i = tid; i < nb; i += 256) {
        int d = lcur[i];
        cursor[node0 + i] = d;
        int dc = d > MAXDEG ? MAXDEG : d;
        int dcp = (dc + 15) & ~15;
        int* p = &csr[(size_t)(node0 + i) * MAXDEG];
        for (int e = dc; e < dcp; ++e) p[e] = n;
    }
}

// Y(bf16) = X @ Wa ; Z(fp32) = X @ Wb + bias.  X: n x 64 fp32, W row-major [j][k].
// 128 nodes/block; thread = 8 nodes (ty) x 8 outputs (tx: 4 Y cols + 4 Z cols).
__global__ __launch_bounds__(256) void k_gemm(const float* __restrict__ X,
                                              const float* __restrict__ Wa,
                                              const float* __restrict__ Wb,
                                              const float* __restrict__ bias,
                                              u16* __restrict__ Y, float* __restrict__ Z, int n) {
    __shared__ float Xs[GB][68];     // ~34.8KB, untransposed; compute reads are broadcasts
    __shared__ float Wc[64][128];    // 32KB: k<64 -> Wa, k>=64 -> Wb
    int tid = threadIdx.x;
    int n0 = blockIdx.x * GB;

    for (int f = tid; f < 1024; f += 256) {
        int j = f >> 4, k4 = (f & 15) * 4;
        *(float4*)&Wc[j][k4]      = *(const float4*)&Wa[(size_t)f * 4];
        *(float4*)&Wc[j][64 + k4] = *(const float4*)&Wb[(size_t)f * 4];
    }
    for (int f = tid; f < GB * 16; f += 256) {
        int r = f >> 4, c4 = (f & 15) * 4;
        int nn = n0 + r;
        float4 xv = (nn < n) ? *(const float4*)&X[(size_t)nn * 64 + c4]
                             : make_float4(0.f, 0.f, 0.f, 0.f);
        *(float4*)&Xs[r][c4] = xv;
    }
    __syncthreads();

    int tx = tid & 15, ty = tid >> 4;
    float acc[8][8];
#pragma unroll
    for (int u = 0; u < 8; ++u)
#pragma unroll
        for (int v = 0; v < 8; ++v) acc[u][v] = 0.f;

#pragma unroll 2
    for (int j = 0; j < 64; ++j) {
        float xs[8];
#pragma unroll
        for (int u = 0; u < 8; ++u) xs[u] = Xs[ty * 8 + u][j];
        float4 wa = *(const float4*)&Wc[j][tx * 4];
        float4 wb = *(const float4*)&Wc[j][64 + tx * 4];
        float ws[8] = {wa.x, wa.y, wa.z, wa.w, wb.x, wb.y, wb.z, wb.w};
#pragma unroll
        for (int u = 0; u < 8; ++u)
#pragma unroll
            for (int v = 0; v < 8; ++v) acc[u][v] += xs[u] * ws[v];
    }

    float4 bv = *(const float4*)&bias[tx * 4];
#pragma unroll
    for (int u = 0; u < 8; ++u) {
        int nn = n0 + ty * 8 + u;
        if (nn < n) {
            ushort4 o;
            o.x = f2b(acc[u][0]); o.y = f2b(acc[u][1]);
            o.z = f2b(acc[u][2]); o.w = f2b(acc[u][3]);
            *(ushort4*)&Y[(size_t)nn * 64 + tx * 4] = o;
            *(float4*)&Z[(size_t)nn * 64 + tx * 4] =
                make_float4(acc[u][4] + bv.x, acc[u][5] + bv.y, acc[u][6] + bv.z, acc[u][7] + bv.w);
        }
    }
}

// Gather core: 4 nodes per wave, 16 lanes per node, 4 bf16 cols per lane.
#define GATHER_CORE(ACC_DONE)                                                        \
    int t = threadIdx.x;                                                             \
    int lane = t & 63;                                                               \
    int g = lane >> 4, q = lane & 15;                                                \
    int node = blockIdx.x * 16 + (t >> 6) * 4 + g;                                   \
    if (node >= n) return;                                                           \
    int d = deg[node];                                                               \
    int dc = d > MAXDEG ? MAXDEG : d;                                                \
    int dcp = (dc + 15) & ~15;                                                       \
    const int* lst = &csr[(size_t)node * MAXDEG];                                    \
    float4 z = *(const float4*)&Z[(size_t)node * 64 + q * 4];                        \
    float4 acc = make_float4(0.f, 0.f, 0.f, 0.f);                                    \
    for (int e = 0; e < dcp; e += 16) {                                              \
        int4 i0 = *(const int4*)&lst[e];                                             \
        int4 i1 = *(const int4*)&lst[e + 4];                                         \
        int4 i2 = *(const int4*)&lst[e + 8];                                         \
        int4 i3 = *(const int4*)&lst[e + 12];                                        \
        uint2 a0 = *(const uint2*)&Y[(size_t)i0.x * 64 + q * 4];                     \
        uint2 a1 = *(const uint2*)&Y[(size_t)i0.y * 64 + q * 4];                     \
        uint2 a2 = *(const uint2*)&Y[(size_t)i0.z * 64 + q * 4];                     \
        uint2 a3 = *(const uint2*)&Y[(size_t)i0.w * 64 + q * 4];                     \
        uint2 a4 = *(const uint2*)&Y[(size_t)i1.x * 64 + q * 4];                     \
        uint2 a5 = *(const uint2*)&Y[(size_t)i1.y * 64 + q * 4];                     \
        uint2 a6 = *(const uint2*)&Y[(size_t)i1.z * 64 + q * 4];                     \
        uint2 a7 = *(const uint2*)&Y[(size_t)i1.w * 64 + q * 4];                     \
        uint2 b0 = *(const uint2*)&Y[(size_t)i2.x * 64 + q * 4];                     \
        uint2 b1 = *(const uint2*)&Y[(size_t)i2.y * 64 + q * 4];                     \
        uint2 b2 = *(const uint2*)&Y[(size_t)i2.z * 64 + q * 4];                     \
        uint2 b3 = *(const uint2*)&Y[(size_t)i2.w * 64 + q * 4];                     \
        uint2 b4 = *(const uint2*)&Y[(size_t)i3.x * 64 + q * 4];                     \
        uint2 b5 = *(const uint2*)&Y[(size_t)i3.y * 64 + q * 4];                     \
        uint2 b6 = *(const uint2*)&Y[(size_t)i3.z * 64 + q * 4];                     \
        uint2 b7 = *(const uint2*)&Y[(size_t)i3.w * 64 + q * 4];                     \
        bacc(acc, a0); bacc(acc, a1); bacc(acc, a2); bacc(acc, a3);                  \
        bacc(acc, a4); bacc(acc, a5); bacc(acc, a6); bacc(acc, a7);                  \
        bacc(acc, b0); bacc(acc, b1); bacc(acc, b2); bacc(acc, b3);                  \
        bacc(acc, b4); bacc(acc, b5); bacc(acc, b6); bacc(acc, b7);                  \
    }                                                                                \
    float inv = 1.0f / (float)(d > 1 ? d : 1);                                       \
    float4 v;                                                                        \
    v.x = acc.x * inv + z.x;                                                         \
    v.y = acc.y * inv + z.y;                                                         \
    v.z = acc.z * inv + z.z;                                                         \
    v.w = acc.w * inv + z.w;                                                         \
    v.x = v.x > 0.f ? v.x : 0.f;                                                     \
    v.y = v.y > 0.f ? v.y : 0.f;                                                     \
    v.z = v.z > 0.f ? v.z : 0.f;                                                     \
    v.w = v.w > 0.f ? v.w : 0.f;                                                     \
    ACC_DONE

__global__ __launch_bounds__(256) void k_gather_l1(const u16* __restrict__ Y,
                                                   const float* __restrict__ Z,
                                                   const int* __restrict__ deg,
                                                   const int* __restrict__ csr,
                                                   float* __restrict__ H, int n) {
    GATHER_CORE({ *(float4*)&H[(size_t)node * 64 + q * 4] = v; })
}

// Layer-2 gather fused with readout dot; one scalar per node.
__global__ __launch_bounds__(256) void k_gather_l2(const u16* __restrict__ Y,
                                                   const float* __restrict__ Z,
                                                   const int* __restrict__ deg,
                                                   const int* __restrict__ csr,
                                                   const float* __restrict__ Wro,
                                                   float* __restrict__ r, int n) {
    GATHER_CORE({
        float4 w = *(const float4*)&Wro[q * 4];
        float s = v.x * w.x + v.y * w.y + v.z * w.z + v.w * w.w;
        s += __shfl_xor(s, 1, 16);
        s += __shfl_xor(s, 2, 16);
        s += __shfl_xor(s, 4, 16);
        s += __shfl_xor(s, 8, 16);
        if (q == 0) r[node] = s;
    })
}

// One block per graph: mean of r over the graph's contiguous node range + bro.
__global__ __launch_bounds__(256) void k_pool(const float* __restrict__ r,
                                              const int* __restrict__ batch,
                                              const float* __restrict__ bro,
                                              float* __restrict__ out, int n) {
    __shared__ float wsum[4];
    int gidx = blockIdx.x;
    int tid = threadIdx.x;
    int lo = 0, hi = n;
    while (lo < hi) { int m = (lo + hi) >> 1; if (batch[m] < gidx) lo = m + 1; else hi = m; }
    int lb = lo;
    lo = 0; hi = n;
    while (lo < hi) { int m = (lo + hi) >> 1; if (batch[m] < gidx + 1) lo = m + 1; else hi = m; }
    int ub = lo;
    float s = 0.f;
    for (int i = lb + tid; i < ub; i += 256) s += r[i];
#pragma unroll
    for (int off = 32; off; off >>= 1) s += __shfl_xor(s, off, 64);
    if ((tid & 63) == 0) wsum[tid >> 6] = s;
    __syncthreads();
    if (tid == 0) {
        float tot = wsum[0] + wsum[1] + wsum[2] + wsum[3];
        int c = ub - lb;
        out[gidx] = tot / (float)(c > 1 ? c : 1) + bro[0];
    }
}

extern "C" void kernel_launch(void* const* d_in, const int* in_sizes, int n_in,
                              void* d_out, int out_size, void* d_ws, size_t ws_size,
                              hipStream_t stream) {
    const float* x   = (const float*)d_in[0];
    const float* Wl1 = (const float*)d_in[1];
    const float* bl1 = (const float*)d_in[2];
    const float* Wr1 = (const float*)d_in[3];
    const float* Wl2 = (const float*)d_in[4];
    const float* bl2 = (const float*)d_in[5];
    const float* Wr2 = (const float*)d_in[6];
    const float* Wro = (const float*)d_in[7];
    const float* bro = (const float*)d_in[8];
    const int* ei    = (const int*)d_in[9];
    const int* batch = (const int*)d_in[10];

    int N = in_sizes[0] / 64;
    int E = in_sizes[9] / 2;
    int G = out_size;
    int NB = (N + 511) >> 9;              // buckets of 512 nodes
    int NC = (E + CHUNK - 1) / CHUNK;     // chunks

    char* ws = (char*)d_ws;
    size_t off = 0;
    auto carve = [&](size_t bytes) {
        void* p = ws + off;
        off += (bytes + 255) & ~(size_t)255;
        return p;
    };
    int*      cursor = (int*)carve((size_t)N * 4);
    int*      csr    = (int*)carve((size_t)N * MAXDEG * 4);
    u16*      y      = (u16*)carve((size_t)(N + 1) * 64 * 2);   // bf16 rows, +1 sentinel
    float*    z      = (float*)carve((size_t)N * 64 * 4);
    float*    h      = (float*)carve((size_t)N * 64 * 4);
    float*    r      = (float*)carve((size_t)N * 4);
    int*      ghist  = (int*)carve((size_t)NB * 4);
    int*      base   = (int*)carve((size_t)NB * 4);
    int*      chist  = (int*)carve((size_t)NB * NC * 4);
    unsigned* ebuf   = (unsigned*)carve((size_t)E * 4);

    k_chunkhist<<<NC, 256, 0, stream>>>(ei, E, NB, NC, chist);
    k_scanA<<<NB, 256, 0, stream>>>(chist, NB, NC, ghist);
    k_scanB<<<1, 256, 0, stream>>>(ghist, NB, base, y, N);
    k_binA<<<NC, 256, 0, stream>>>(ei, E, NB, NC, chist, base, ghist, ebuf);
    k_binB<<<NB, 256, 0, stream>>>(ebuf, base, ghist, cursor, csr, N);
    k_gemm<<<(N + GB - 1) / GB, 256, 0, stream>>>(x, Wl1, Wr1, bl1, y, z, N);
    k_gather_l1<<<(N + 15) / 16, 256, 0, stream>>>(y, z, cursor, csr, h, N);
    k_gemm<<<(N + GB - 1) / GB, 256, 0, stream>>>(h, Wl2, Wr2, bl2, y, z, N);
    k_gather_l2<<<(N + 15) / 16, 256, 0, stream>>>(y, z, cursor, csr, Wro, r, N);
    k_pool<<<G, 256, 0, stream>>>(r, batch, bro, (float*)d_out, N);
}